// Round 8
// baseline (170.644 us; speedup 1.0000x reference)
//
#include <hip/hip_runtime.h>
#include <hip/hip_bf16.h>
#include <stdint.h>

#define DIMF   1024
#define HEADS  16
#define HD     64
#define BB     2
#define NN     2048
#define NKP    2112   // 2049 keys padded to 33*64
#define NTILE  33

typedef __attribute__((ext_vector_type(8))) __bf16 bf16x8;
typedef __attribute__((ext_vector_type(4))) float  f32x4;

__device__ __forceinline__ float b2f(uint16_t h) {
  union { uint32_t u; float f; } v; v.u = ((uint32_t)h) << 16; return v.f;
}
__device__ __forceinline__ uint16_t f2b(float f) {
  union { float f; uint32_t u; } v; v.f = f;
  uint32_t r = v.u + 0x7FFFu + ((v.u >> 16) & 1u);
  return (uint16_t)(r >> 16);
}
// packed f32x2 -> bf16x2 via the COMPILER intrinsic (operand order guaranteed)
__device__ __forceinline__ uint32_t pack2(float a, float b) {
  __hip_bfloat162 h = __float22bfloat162_rn(float2{a, b});
  union { __hip_bfloat162 h; uint32_t u; } v; v.h = h; return v.u;
}

// async global->LDS DMA, 16B per lane. LDS dest = wave-uniform base + lane*16.
__device__ __forceinline__ void gl_lds16(const void* g, void* l) {
  __builtin_amdgcn_global_load_lds(
      (const __attribute__((address_space(1))) void*)g,
      (__attribute__((address_space(3))) void*)l, 16, 0, 0);
}

// ---------------- fp32 -> bf16 bulk convert (float4 loads) ----------------
__global__ __launch_bounds__(256) void cvt_f32_bf16(const float* __restrict__ src,
                                                    uint16_t* __restrict__ dst, int n4) {
  int i = blockIdx.x * 256 + threadIdx.x;
  if (i < n4) {
    float4 v = *(const float4*)&src[i * 4];
    uint16_t* d = dst + i * 4;
    d[0] = f2b(v.x); d[1] = f2b(v.y); d[2] = f2b(v.z); d[3] = f2b(v.w);
  }
}

// -------- transpose + convert (fp32 M x N -> bf16 N x M), 32x32 tiles --------
__global__ __launch_bounds__(256) void transpose_k(const float* __restrict__ src,
                                                   uint16_t* __restrict__ dst, int M, int N) {
  __shared__ uint16_t tile[32][33];
  int bx = blockIdx.x * 32, by = blockIdx.y * 32;
  int x = threadIdx.x, y0 = threadIdx.y;
#pragma unroll
  for (int i = 0; i < 32; i += 8)
    tile[y0 + i][x] = f2b(src[(size_t)(by + y0 + i) * N + bx + x]);
  __syncthreads();
#pragma unroll
  for (int i = 0; i < 32; i += 8)
    dst[(size_t)(bx + y0 + i) * M + by + x] = tile[x][y0 + i];
}

// ---------------- fill void K/V rows + zero padding ----------------
__global__ __launch_bounds__(256) void fill_void(const float* __restrict__ vk,
                                                 const float* __restrict__ vv,
                                                 uint16_t* __restrict__ k_ws,
                                                 uint16_t* __restrict__ vt_ws) {
  int idx = blockIdx.x * 256 + threadIdx.x;   // 0 .. 131071 = BB*HEADS*64*64
  int dd = idx & 63;
  int r  = (idx >> 6) & 63;      // padded key row 2048+r
  int bh = idx >> 12;            // 0..31
  int h  = bh & (HEADS - 1);
  uint16_t kv  = (r == 0) ? f2b(vk[h * HD + dd]) : (uint16_t)0;
  uint16_t vvv = (r == 0) ? f2b(vv[h * HD + dd]) : (uint16_t)0;
  k_ws[((size_t)bh * NKP + NN + r) * HD + dd]  = kv;
  vt_ws[((size_t)bh * HD + dd) * NKP + NN + r] = vvv;
}

// ---------------- GEMM: C[M,N] = A[M,K] * Bt[N,K]^T, bf16 in, fp32 acc ----------------
template<int EPI>
__global__ __launch_bounds__(256) void gemm_bt(const uint16_t* __restrict__ A,
                                               const uint16_t* __restrict__ Bt,
                                               int K, int Nout,
                                               uint16_t* __restrict__ o0,
                                               uint16_t* __restrict__ o1,
                                               uint16_t* __restrict__ o2,
                                               float* __restrict__ fo,
                                               const float* __restrict__ bias) {
  __shared__ uint16_t lds_a[128][32];   // linear: required by global_load_lds
  __shared__ uint16_t lds_b[128][32];
  const int m0 = blockIdx.y * 128, n0 = blockIdx.x * 128;
  const int tid = threadIdx.x, lane = tid & 63, wid = tid >> 6;
  const int wm = (wid >> 1) * 64, wn = (wid & 1) * 64;
  const int lr = lane & 15, lg = lane >> 4;
  f32x4 acc[4][4] = {};
  for (int k0 = 0; k0 < K; k0 += 32) {
    __syncthreads();
#pragma unroll
    for (int it = 0; it < 2; ++it) {
      const int chunk = wid * 2 + it;            // 0..7 (1 KiB each)
      const int o = chunk * 1024 + lane * 16;
      const int r = o >> 6, cb = o & 63;
      gl_lds16((const char*)&A[(size_t)(m0 + r) * K + k0] + cb,
               (char*)&lds_a[0][0] + chunk * 1024);
      gl_lds16((const char*)&Bt[(size_t)(n0 + r) * K + k0] + cb,
               (char*)&lds_b[0][0] + chunk * 1024);
    }
    __syncthreads();
    bf16x8 af[4], bf[4];
#pragma unroll
    for (int i = 0; i < 4; ++i)
      af[i] = *(const bf16x8*)((const char*)&lds_a[0][0] + (wm + i * 16 + lr) * 64 + lg * 16);
#pragma unroll
    for (int j = 0; j < 4; ++j)
      bf[j] = *(const bf16x8*)((const char*)&lds_b[0][0] + (wn + j * 16 + lr) * 64 + lg * 16);
#pragma unroll
    for (int i = 0; i < 4; ++i)
#pragma unroll
      for (int j = 0; j < 4; ++j)
        acc[i][j] = __builtin_amdgcn_mfma_f32_16x16x32_bf16(af[i], bf[j], acc[i][j], 0, 0, 0);
  }
#pragma unroll
  for (int i = 0; i < 4; ++i)
#pragma unroll
    for (int j = 0; j < 4; ++j)
#pragma unroll
      for (int r = 0; r < 4; ++r) {
        int mg = m0 + wm + i * 16 + lg * 4 + r;   // C row = m (m89 layout)
        int ng = n0 + wn + j * 16 + lr;            // C col = n
        float v = acc[i][j][r];
        if (EPI == 0) {
          int b = mg >> 11, n = mg & (NN - 1);
          int which = ng >> 10, rem = ng & (DIMF - 1), h = rem >> 6, dd = rem & 63;
          int bh = b * HEADS + h;
          uint16_t bv = f2b(v);
          if (which == 0)      o0[((size_t)bh * NN + n) * HD + dd] = bv;
          else if (which == 1) o1[((size_t)bh * NKP + n) * HD + dd] = bv;
          else                 o2[((size_t)bh * HD + dd) * NKP + n] = bv;  // V transposed
        } else {
          fo[(size_t)mg * Nout + ng] = v + bias[ng];   // FP32 output
        }
      }
}

// ------------- flash attention: swapped QK^T, LDS-staged P, 16x16x32 PV -------------
// 4 waves x 32 q-rows. S^T = mfma(K, Q): lane (lg,lr) holds P[key=c*16+lg*4+r][q=lr].
// P packed to bf16 pairs with the compiler intrinsic and staged to per-wave LDS as
// ldsp[q][key]; PV then runs EXACTLY like round-6's proven path:
//   A = P[q=lr][k=key], B = V^T[key][d=lr] -> O[q=lg*4+r][d=cd*16+lr].
// Fixed-max softmax (|logit| <= ~2); zero-padded phantom keys give p=1, minus 63.
// K/V double-buffered via global_load_lds, XOR-swizzled reads (T2/G21).
__global__ __launch_bounds__(256) void attn_k(const uint16_t* __restrict__ q_ws,
                                              const uint16_t* __restrict__ k_ws,
                                              const uint16_t* __restrict__ vt_ws,
                                              const float* __restrict__ trace,
                                              const float* __restrict__ factor,
                                              uint16_t* __restrict__ o_ws) {
  __shared__ uint16_t ldsk[2][64][64];       // [buf][key][d], swizzled cols
  __shared__ uint16_t ldsv[2][64][64];       // [buf][d][key], swizzled cols
  __shared__ uint16_t ldsp[4][2][16][72];    // [wave][qhalf][q][key(+pad)]
  const int qb = blockIdx.x, h = blockIdx.y, b = blockIdx.z;
  const int bh = b * HEADS + h;
  const int tid = threadIdx.x, lane = tid & 63, wid = tid >> 6;
  const int lr = lane & 15, lg = lane >> 4;

  const float temp = fmaxf(1.0f + fabsf(trace[h]) * factor[h], 1.0f);
  const float sl2  = (0.03125f / temp) * 1.44269504f;   // scale * log2(e)

  const int qrow0 = qb * 128 + wid * 32;
  const uint16_t* qpa = q_ws + ((size_t)bh * NN + qrow0 + lr) * HD;
  const uint16_t* qpb = qpa + 16 * HD;
  bf16x8 qfa[2], qfb[2];
#pragma unroll
  for (int kk = 0; kk < 2; ++kk) {
    qfa[kk] = *(const bf16x8*)(qpa + kk * 32 + lg * 8);
    qfb[kk] = *(const bf16x8*)(qpb + kk * 32 + lg * 8);
  }

  f32x4 acca[4] = {}, accb[4] = {};
  float lsa = 0.f, lsb = 0.f;

#define STAGE(buf, t)                                                              \
  {                                                                                \
    const int t0_ = (t) * 64;                                                      \
    _Pragma("unroll")                                                              \
    for (int it = 0; it < 2; ++it) {                                               \
      const int chunk = wid * 2 + it;                                              \
      const int o = chunk * 1024 + lane * 16;                                      \
      const int r = o >> 7, cb = o & 127;                                          \
      const int scb = cb ^ ((r & 7) << 4);                                         \
      gl_lds16((const char*)&k_ws[((size_t)bh * NKP + t0_ + r) * HD] + scb,        \
               (char*)&ldsk[buf][0][0] + chunk * 1024);                            \
      gl_lds16((const char*)&vt_ws[((size_t)bh * HD + r) * NKP + t0_] + scb,       \
               (char*)&ldsv[buf][0][0] + chunk * 1024);                            \
    }                                                                              \
  }

  STAGE(0, 0);
  __syncthreads();   // vmcnt(0) drained: tile 0 visible

  int cur = 0;
  for (int t = 0; t < NTILE; ++t) {
    const int tn = (t + 1 < NTILE) ? t + 1 : t;   // last iter: harmless restage
    STAGE(cur ^ 1, tn);

    // S^T = K Q^T per 16-key chunk; exp2; pack pairs; stage to ldsp[q][key]
#pragma unroll
    for (int c = 0; c < 4; ++c) {
      bf16x8 kf0, kf1;
      {
        const int row = c * 16 + lr;
        const int rsw = (row & 7) << 4;
        kf0 = *(const bf16x8*)((const char*)&ldsk[cur][0][0] + row * 128 + ((lg * 16) ^ rsw));
        kf1 = *(const bf16x8*)((const char*)&ldsk[cur][0][0] + row * 128 + ((64 + lg * 16) ^ rsw));
      }
      f32x4 sa = {}, sb = {};
      sa = __builtin_amdgcn_mfma_f32_16x16x32_bf16(kf0, qfa[0], sa, 0, 0, 0);
      sa = __builtin_amdgcn_mfma_f32_16x16x32_bf16(kf1, qfa[1], sa, 0, 0, 0);
      sb = __builtin_amdgcn_mfma_f32_16x16x32_bf16(kf0, qfb[0], sb, 0, 0, 0);
      sb = __builtin_amdgcn_mfma_f32_16x16x32_bf16(kf1, qfb[1], sb, 0, 0, 0);
      float p0 = exp2f(sa[0] * sl2), p1 = exp2f(sa[1] * sl2);
      float p2 = exp2f(sa[2] * sl2), p3 = exp2f(sa[3] * sl2);
      lsa += (p0 + p1) + (p2 + p3);
      *(uint32_t*)&ldsp[wid][0][lr][c * 16 + lg * 4]     = pack2(p0, p1);
      *(uint32_t*)&ldsp[wid][0][lr][c * 16 + lg * 4 + 2] = pack2(p2, p3);
      p0 = exp2f(sb[0] * sl2); p1 = exp2f(sb[1] * sl2);
      p2 = exp2f(sb[2] * sl2); p3 = exp2f(sb[3] * sl2);
      lsb += (p0 + p1) + (p2 + p3);
      *(uint32_t*)&ldsp[wid][1][lr][c * 16 + lg * 4]     = pack2(p0, p1);
      *(uint32_t*)&ldsp[wid][1][lr][c * 16 + lg * 4 + 2] = pack2(p2, p3);
    }
    // ordering fence: u32 LDS writes -> bf16x8 LDS reads, same wave, no barrier
    asm volatile("" ::: "memory");
    __builtin_amdgcn_sched_barrier(0);

    // O += P V (round-6-proven pattern), V^T fragments shared by both q-halves
#pragma unroll
    for (int kk = 0; kk < 2; ++kk) {
      bf16x8 pfa = *(const bf16x8*)&ldsp[wid][0][lr][kk * 32 + lg * 8];
      bf16x8 pfb = *(const bf16x8*)&ldsp[wid][1][lr][kk * 32 + lg * 8];
#pragma unroll
      for (int cd = 0; cd < 4; ++cd) {
        const int row = cd * 16 + lr;
        const int cbb = (kk * 64 + lg * 16) ^ ((row & 7) << 4);
        bf16x8 vf = *(const bf16x8*)((const char*)&ldsv[cur][0][0] + row * 128 + cbb);
        acca[cd] = __builtin_amdgcn_mfma_f32_16x16x32_bf16(pfa, vf, acca[cd], 0, 0, 0);
        accb[cd] = __builtin_amdgcn_mfma_f32_16x16x32_bf16(pfb, vf, accb[cd], 0, 0, 0);
      }
    }
    __syncthreads();   // drains vmcnt(0): next tile landed; all reads of cur done
    cur ^= 1;
  }

  // l for q=lr: reduce over lg groups; route to output rows (q=lg*4+r) via shfl
  lsa += __shfl_xor(lsa, 16); lsa += __shfl_xor(lsa, 32);
  lsb += __shfl_xor(lsb, 16); lsb += __shfl_xor(lsb, 32);

#pragma unroll
  for (int r = 0; r < 4; ++r) {
    const int src = lg * 4 + r;                    // lane holding l for this out row
    const float inva = 1.0f / (__shfl(lsa, src) - 63.0f);
    const float invb = 1.0f / (__shfl(lsb, src) - 63.0f);
    const int na = qrow0 + lg * 4 + r;
    size_t basea = ((size_t)b * NN + na) * DIMF + h * HD;
    size_t baseb = basea + (size_t)16 * DIMF;
#pragma unroll
    for (int cd = 0; cd < 4; ++cd) {
      o_ws[basea + cd * 16 + lr] = f2b(acca[cd][r] * inva);
      o_ws[baseb + cd * 16 + lr] = f2b(accb[cd][r] * invb);
    }
  }
}

extern "C" void kernel_launch(void* const* d_in, const int* in_sizes, int n_in,
                              void* d_out, int out_size, void* d_ws, size_t ws_size,
                              hipStream_t stream) {
  const float* x      = (const float*)d_in[0];
  const float* wqkv   = (const float*)d_in[1];
  const float* wout   = (const float*)d_in[2];
  const float* bout   = (const float*)d_in[3];
  // d_in[4] = void_q: unused (void query row is dropped by the reference)
  const float* voidk  = (const float*)d_in[5];
  const float* voidv  = (const float*)d_in[6];
  const float* trace  = (const float*)d_in[7];
  const float* factor = (const float*)d_in[8];
  float* out = (float*)d_out;           // reference output dtype is FP32

  uint16_t* ws    = (uint16_t*)d_ws;
  uint16_t* x_bf  = ws;                       // 2*2048*1024  = 4,194,304 elems
  uint16_t* o_ws  = x_bf;                     // ALIAS: x_bf dead after gemm<0>
  uint16_t* wqkvT = x_bf  + 4194304;          // 3072*1024    = 3,145,728
  uint16_t* woutT = wqkvT + 3145728;          // 1024*1024    = 1,048,576
  uint16_t* q_ws  = woutT + 1048576;          // 2*16*2048*64 = 4,194,304
  uint16_t* k_ws  = q_ws  + 4194304;          // 2*16*2112*64 = 4,325,376
  uint16_t* vt_ws = k_ws  + 4325376;          // 4,325,376   (total ~42.5 MB)

  cvt_f32_bf16<<<dim3(4194304 / 4 / 256), dim3(256), 0, stream>>>(x, x_bf, 4194304 / 4);
  transpose_k<<<dim3(3072 / 32, 1024 / 32), dim3(32, 8), 0, stream>>>(wqkv, wqkvT, 1024, 3072);
  transpose_k<<<dim3(1024 / 32, 1024 / 32), dim3(32, 8), 0, stream>>>(wout, woutT, 1024, 1024);
  fill_void<<<dim3(512), dim3(256), 0, stream>>>(voidk, voidv, k_ws, vt_ws);
  gemm_bt<0><<<dim3(3072 / 128, 4096 / 128), dim3(256), 0, stream>>>(
      x_bf, wqkvT, 1024, 3072, q_ws, k_ws, vt_ws, nullptr, nullptr);
  attn_k<<<dim3(NN / 128, HEADS, BB), dim3(256), 0, stream>>>(
      q_ws, k_ws, vt_ws, trace, factor, o_ws);
  gemm_bt<1><<<dim3(1024 / 128, 4096 / 128), dim3(256), 0, stream>>>(
      o_ws, woutT, 1024, 1024, nullptr, nullptr, nullptr, out, bout);
}